// Round 13
// baseline (312.154 us; speedup 1.0000x reference)
//
#include <hip/hip_runtime.h>
#include <hip/hip_bf16.h>

using bf16 = __hip_bfloat16;
typedef __bf16 bf16x8_t __attribute__((ext_vector_type(8)));
typedef float f32x4_t __attribute__((ext_vector_type(4)));

// ---------------------------------------------------------------- helpers
__device__ __forceinline__ void gl16(bf16* l, const bf16* g) {
  // async global->LDS, 16B per lane; LDS dest must be linear (base + lane*16)
  __builtin_amdgcn_global_load_lds(
      (const __attribute__((address_space(1))) unsigned int*)g,
      (__attribute__((address_space(3))) unsigned int*)l, 16, 0, 0);
}

#define BARRIER() do { asm volatile("" ::: "memory"); __builtin_amdgcn_s_barrier(); asm volatile("" ::: "memory"); } while (0)
#define WAITVM(N) asm volatile("s_waitcnt vmcnt(" #N ")" ::: "memory")
#define LGKM0() asm volatile("s_waitcnt lgkmcnt(0)" ::: "memory")

// ---------------------------------------------------------------- prep: transpose both W (f32 -> bf16, [R][C] -> [C][R])
__global__ __launch_bounds__(256) void prep_t(const float* __restrict__ Wqkv,
                                              const float* __restrict__ Wout,
                                              bf16* __restrict__ w1t,
                                              bf16* __restrict__ w2t) {
  __shared__ float t[32][33];
  const int bid = blockIdx.x;
  const float* in; bf16* out; int R, C, gx, gy;
  if (bid < 3072) {
    in = Wqkv; out = w1t; R = 1024; C = 3072;
    gx = bid % 96; gy = bid / 96;
  } else {
    int idx = bid - 3072; in = Wout; out = w2t; R = 1024; C = 1024;
    gx = idx & 31; gy = idx >> 5;
  }
  int bx = gx * 32, by = gy * 32;
  int tx = threadIdx.x & 31, ty = threadIdx.x >> 5;  // ty 0..7
#pragma unroll
  for (int r = 0; r < 32; r += 8)
    t[ty + r][tx] = in[(size_t)(by + ty + r) * C + bx + tx];
  __syncthreads();
#pragma unroll
  for (int r = 0; r < 32; r += 8)
    out[(size_t)(bx + ty + r) * R + by + tx] = __float2bfloat16(t[tx][ty + r]);
}

// ---------------------------------------------------------------- shared GEMM pieces (R11-verified)
__device__ __forceinline__ void readA(const bf16* lb, int half, int wr, int lr, int lg, int exr,
                                      bf16x8_t (&af)[4][2]) {
  const bf16* ab = lb + half * 8192;
#pragma unroll
  for (int mi = 0; mi < 4; ++mi) {
    int R = wr * 64 + mi * 16 + lr;
    af[mi][0] = *(const bf16x8_t*)(ab + R * 64 + ((lg * 8) ^ exr));
    af[mi][1] = *(const bf16x8_t*)(ab + R * 64 + ((32 + lg * 8) ^ exr));
  }
}
__device__ __forceinline__ void readB(const bf16* lb, int half, int wc, int lr, int lg, int exr,
                                      bf16x8_t (&bfr)[2][2]) {
  const bf16* bb = lb + (2 + half) * 8192;
#pragma unroll
  for (int ni = 0; ni < 2; ++ni) {
    int R = wc * 32 + ni * 16 + lr;
    bfr[ni][0] = *(const bf16x8_t*)(bb + R * 64 + ((lg * 8) ^ exr));
    bfr[ni][1] = *(const bf16x8_t*)(bb + R * 64 + ((32 + lg * 8) ^ exr));
  }
}

template <int MH, int NH>
__device__ __forceinline__ void mfma16(bf16x8_t (&af)[4][2], bf16x8_t (&bfr)[2][2],
                                       f32x4_t (&acc)[8][4]) {
  __builtin_amdgcn_s_setprio(1);
#pragma unroll
  for (int mi = 0; mi < 4; ++mi)
#pragma unroll
    for (int ni = 0; ni < 2; ++ni) {
      f32x4_t& a = acc[MH * 4 + mi][NH * 2 + ni];
      a = __builtin_amdgcn_mfma_f32_16x16x32_bf16(af[mi][0], bfr[ni][0], a, 0, 0, 0);
      a = __builtin_amdgcn_mfma_f32_16x16x32_bf16(af[mi][1], bfr[ni][1], a, 0, 0, 0);
    }
  __builtin_amdgcn_s_setprio(0);
}

// ---------------------------------------------------------------- GEMM1: A read DIRECTLY as f32 (T14 reg-staged cvt)
// C[16384, N=NWGX*256] = cvt_bf16(Af) @ Bt^T + bias -> bf16. K=1024, persistent grid 256x512.
// A-path: ph1-slot writes A(g+1,h0) [regs loaded at ph3(g-1)] + issues reg-loads A(g+1,h1);
// ph3-slot writes A(g+1,h1) + loads A(g+2,h0). B-path: unchanged gl16 (ph2: B(g+1,h1),
// ph4: B(g+2,h0)). ph4: vmcnt(6) drains B(g+1,h1) [leaves A4(g+2,h0)+B2(g+2,h0)];
// lgkmcnt(0) makes ds_writes visible before the barrier. All vm-waits >=2 phases after issue.
// LDS layout/swizzle identical to the bf16 kernel (linear dest, pre-swizzled source col).
template <int NWGX>
__global__ __launch_bounds__(512, 2) void gemm256f(const float* __restrict__ Af,
                                                   const bf16* __restrict__ Bt,
                                                   const float* __restrict__ bias,
                                                   bf16* __restrict__ Cv) {
  constexpr int K = 1024;
  constexpr int N = NWGX * 256;
  constexpr int TT = NWGX / 4;
  constexpr int G = TT * 16;
  constexpr int CPX = NWGX * 8;

  __shared__ __align__(16) bf16 lds[65536];
  const int tid = threadIdx.x;
  const int bx = blockIdx.x;

  const int wid = tid >> 6, lane = tid & 63;
  const int wr = wid >> 2, wc = wid & 3;
  const int lr = lane & 15, lg = lane >> 4;
  const int exr = (lr & 7) << 3;

  const int srow = tid >> 3;
  const int colg = ((((tid & 7) * 16) ^ ((srow & 7) << 4)) >> 1);
  const int browc0 = (srow >> 5) * 64 + (srow & 31);

  auto tileMN = [&](int tt, int& m0, int& n0) {
    int orig = bx + (tt << 8);
    int swz = (orig & 7) * CPX + (orig >> 3);
    m0 = (swz / NWGX) * 256;
    n0 = (swz % NWGX) * 256;
  };

  float4 rA[4];  // pending A chunk (one half-tile worth per thread)
  auto loadA = [&](int g, int h) {
    if (g >= G) return;
    int m0, n0; tileMN(g >> 4, m0, n0);
    const float* s0 = Af + (size_t)(m0 + h * 64 + srow) * K + (g & 15) * 64 + colg;
    const float* s1 = s0 + (size_t)128 * K;
    rA[0] = *(const float4*)s0;
    rA[1] = *(const float4*)(s0 + 4);
    rA[2] = *(const float4*)s1;
    rA[3] = *(const float4*)(s1 + 4);
  };
  auto writeA = [&](int g, int h) {  // cvt + ds_write (compiler inserts the vm-wait on rA)
    if (g >= G) return;
    bf16* l = lds + (g & 1) * 32768 + h * 8192 + tid * 8;
    union { float4 f4[2]; float f[8]; } u0, u1;
    u0.f4[0] = rA[0]; u0.f4[1] = rA[1];
    u1.f4[0] = rA[2]; u1.f4[1] = rA[3];
    bf16x8_t v0, v1;
#pragma unroll
    for (int j = 0; j < 8; ++j) { v0[j] = (__bf16)u0.f[j]; v1[j] = (__bf16)u1.f[j]; }
    *(bf16x8_t*)l = v0;
    *(bf16x8_t*)(l + 4096) = v1;
  };
  auto stageB = [&](int g, int h) {
    if (g >= G) return;
    int m0, n0; tileMN(g >> 4, m0, n0);
    const bf16* g0 = Bt + (size_t)(n0 + browc0 + h * 32) * K + (g & 15) * 64 + colg;
    bf16* l = lds + (g & 1) * 32768 + (2 + h) * 8192 + tid * 8;
    gl16(l, g0); gl16(l + 4096, g0 + (size_t)128 * K);
  };

  f32x4_t acc[8][4] = {};
  bf16x8_t af1[4][2], af2[4][2], b0[2][2], b1[2][2];

  // prologue: A(0,*) via reg-cvt; B(0,*) gl16; prefetch {A(1,h0) regs, B(1,h0) gl16}
  loadA(0, 0);
  stageB(0, 0); stageB(0, 1);
  writeA(0, 0);
  loadA(0, 1);
  writeA(0, 1);
  loadA(1, 0);
  stageB(1, 0);
  WAITVM(6);   // drain B(0,*); leaves A4(1,h0)+B2(1,h0)
  LGKM0();     // prologue ds_writes visible
  BARRIER();
  readA(lds, 0, wr, lr, lg, exr, af1);
  readB(lds, 0, wc, lr, lg, exr, b0);

  for (int g = 0; g < G; ++g) {
    const bf16* cb = lds + (g & 1) * 32768;
    const bf16* nb = lds + ((g & 1) ^ 1) * 32768;

    // ph1: Q(0,0); slot: write A(g+1,h0), issue A-loads (g+1,h1)
    writeA(g + 1, 0);
    loadA(g + 1, 1);
    BARRIER();
    readB(cb, 1, wc, lr, lg, exr, b1);
    mfma16<0, 0>(af1, b0, acc);

    // ph2: Q(0,1); slot: stage B(g+1,h1)
    stageB(g + 1, 1);
    BARRIER();
    readA(cb, 1, wr, lr, lg, exr, af2);
    mfma16<0, 1>(af1, b1, acc);

    // ph3: Q(1,0); slot: write A(g+1,h1), issue A-loads (g+2,h0)
    writeA(g + 1, 1);
    loadA(g + 2, 0);
    BARRIER();
    mfma16<1, 0>(af2, b0, acc);

    // ph4: Q(1,1); slot: stage B(g+2,h0); counted wait; lgkm drain
    stageB(g + 2, 0);
    if (g < G - 2) { WAITVM(6); } else { WAITVM(0); }
    LGKM0();
    BARRIER();
    if (g < G - 1) {
      readA(nb, 0, wr, lr, lg, exr, af1);
      readB(nb, 0, wc, lr, lg, exr, b0);
    }
    mfma16<1, 1>(af2, b1, acc);

    if ((g & 15) == 15) {
      BARRIER();  // keep dump stores out of the last phase's read window
      int m0, n0; tileMN(g >> 4, m0, n0);
      float bv[4];
#pragma unroll
      for (int n = 0; n < 4; ++n) bv[n] = bias[n0 + wc * 64 + n * 16 + lr];
#pragma unroll
      for (int m = 0; m < 8; ++m) {
        int row = m0 + wr * 128 + m * 16 + lg * 4;
#pragma unroll
        for (int j = 0; j < 4; ++j) {
#pragma unroll
          for (int n = 0; n < 4; ++n) {
            int col = n0 + wc * 64 + n * 16 + lr;
            Cv[(size_t)(row + j) * N + col] = __float2bfloat16(acc[m][n][j] + bv[n]);
            acc[m][n][j] = 0.f;
          }
        }
      }
    }
  }
}

// ---------------------------------------------------------------- GEMM2: bf16 A (exact R11-verified kernel)
template <int OUT_BF16, int NWGX>
__global__ __launch_bounds__(512, 2) void gemm256p(const bf16* __restrict__ A,
                                                   const bf16* __restrict__ Bt,
                                                   const float* __restrict__ bias,
                                                   void* __restrict__ Cv) {
  constexpr int K = 1024;
  constexpr int N = NWGX * 256;
  constexpr int TT = NWGX / 4;
  constexpr int G = TT * 16;
  constexpr int CPX = NWGX * 8;

  __shared__ __align__(16) bf16 lds[65536];
  const int tid = threadIdx.x;
  const int bx = blockIdx.x;

  const int wid = tid >> 6, lane = tid & 63;
  const int wr = wid >> 2, wc = wid & 3;
  const int lr = lane & 15, lg = lane >> 4;
  const int exr = (lr & 7) << 3;

  const int srow = tid >> 3;
  const int colg = ((((tid & 7) * 16) ^ ((srow & 7) << 4)) >> 1);
  const int browc0 = (srow >> 5) * 64 + (srow & 31);

  auto tileMN = [&](int tt, int& m0, int& n0) {
    int orig = bx + (tt << 8);
    int swz = (orig & 7) * CPX + (orig >> 3);
    m0 = (swz / NWGX) * 256;
    n0 = (swz % NWGX) * 256;
  };

  auto stageA = [&](int g, int h) {
    if (g >= G) return;
    int m0, n0; tileMN(g >> 4, m0, n0);
    const bf16* g0 = A + (size_t)(m0 + h * 64 + srow) * K + (g & 15) * 64 + colg;
    bf16* l = lds + (g & 1) * 32768 + h * 8192 + tid * 8;
    gl16(l, g0); gl16(l + 4096, g0 + (size_t)128 * K);
  };
  auto stageB = [&](int g, int h) {
    if (g >= G) return;
    int m0, n0; tileMN(g >> 4, m0, n0);
    const bf16* g0 = Bt + (size_t)(n0 + browc0 + h * 32) * K + (g & 15) * 64 + colg;
    bf16* l = lds + (g & 1) * 32768 + (2 + h) * 8192 + tid * 8;
    gl16(l, g0); gl16(l + 4096, g0 + (size_t)128 * K);
  };

  f32x4_t acc[8][4] = {};
  bf16x8_t af1[4][2], af2[4][2], b0[2][2], b1[2][2];

  stageA(0, 0); stageB(0, 0); stageA(0, 1); stageB(0, 1);
  stageA(1, 0); stageB(1, 0);
  WAITVM(4);
  BARRIER();
  readA(lds, 0, wr, lr, lg, exr, af1);
  readB(lds, 0, wc, lr, lg, exr, b0);

  for (int g = 0; g < G; ++g) {
    const bf16* cb = lds + (g & 1) * 32768;
    const bf16* nb = lds + ((g & 1) ^ 1) * 32768;

    stageA(g + 1, 1);
    BARRIER();
    readB(cb, 1, wc, lr, lg, exr, b1);
    mfma16<0, 0>(af1, b0, acc);

    stageB(g + 1, 1);
    BARRIER();
    readA(cb, 1, wr, lr, lg, exr, af2);
    mfma16<0, 1>(af1, b1, acc);

    stageA(g + 2, 0);
    BARRIER();
    mfma16<1, 0>(af2, b0, acc);

    stageB(g + 2, 0);
    if (g < G - 2) { WAITVM(4); } else { WAITVM(0); }
    BARRIER();
    if (g < G - 1) {
      readA(nb, 0, wr, lr, lg, exr, af1);
      readB(nb, 0, wc, lr, lg, exr, b0);
    }
    mfma16<1, 1>(af2, b1, acc);

    if ((g & 15) == 15) {
      BARRIER();
      int m0, n0; tileMN(g >> 4, m0, n0);
      float bv[4];
#pragma unroll
      for (int n = 0; n < 4; ++n) bv[n] = bias[n0 + wc * 64 + n * 16 + lr];
#pragma unroll
      for (int m = 0; m < 8; ++m) {
        int row = m0 + wr * 128 + m * 16 + lg * 4;
#pragma unroll
        for (int j = 0; j < 4; ++j) {
#pragma unroll
          for (int n = 0; n < 4; ++n) {
            int col = n0 + wc * 64 + n * 16 + lr;
            float v = acc[m][n][j] + bv[n];
            if (OUT_BF16)
              ((bf16*)Cv)[(size_t)(row + j) * N + col] = __float2bfloat16(v);
            else
              ((float*)Cv)[(size_t)(row + j) * N + col] = v;
            acc[m][n][j] = 0.f;
          }
        }
      }
    }
  }
}

// ---------------------------------------------------------------- per-token head-mixing attention (MFMA)
#define PSTR 48
__global__ __launch_bounds__(256) void attn_tok(const bf16* __restrict__ qkv,
                                                bf16* __restrict__ out) {
  __shared__ __align__(16) bf16 vs[4][1024];
  __shared__ __align__(16) bf16 ps[4][16 * PSTR];
  const int w = threadIdx.x >> 6, l = threadIdx.x & 63;
  const int t = blockIdx.x * 4 + w;
  const int lr = l & 15, lg = l >> 4;
  const bf16* base = qkv + (size_t)t * 3072;

  bf16x8_t v0 = *(const bf16x8_t*)(base + 2048 + l * 16);
  bf16x8_t v1 = *(const bf16x8_t*)(base + 2048 + l * 16 + 8);
  *(bf16x8_t*)(&vs[w][l * 16]) = v0;
  *(bf16x8_t*)(&vs[w][l * 16 + 8]) = v1;

  *(unsigned long long*)(&ps[w][(l >> 2) * PSTR + 16 + (l & 3) * 4]) = 0ULL;

  const bf16* qp = base + lr * 64 + lg * 8;
  const bf16* kp = base + 1024 + lr * 64 + lg * 8;
  bf16x8_t qa0 = *(const bf16x8_t*)qp;
  bf16x8_t ka0 = *(const bf16x8_t*)kp;
  bf16x8_t qa1 = *(const bf16x8_t*)(qp + 32);
  bf16x8_t ka1 = *(const bf16x8_t*)(kp + 32);
  f32x4_t s = {};
  s = __builtin_amdgcn_mfma_f32_16x16x32_bf16(qa0, ka0, s, 0, 0, 0);
  s = __builtin_amdgcn_mfma_f32_16x16x32_bf16(qa1, ka1, s, 0, 0, 0);

#pragma unroll
  for (int j = 0; j < 4; ++j) {
    float x = s[j] * 0.125f;
    float mx = x;
#pragma unroll
    for (int off = 8; off; off >>= 1) mx = fmaxf(mx, __shfl_xor(mx, off, 16));
    float e = __expf(x - mx);
    float sum = e;
#pragma unroll
    for (int off = 8; off; off >>= 1) sum += __shfl_xor(sum, off, 16);
    ps[w][(lg * 4 + j) * PSTR + lr] = __float2bfloat16(e / sum);
  }

  bf16x8_t pf = *(const bf16x8_t*)(&ps[w][lr * PSTR + lg * 8]);
  bf16x8_t vf[4] = {};
  if (l < 32) {
#pragma unroll
    for (int c = 0; c < 4; ++c)
#pragma unroll
      for (int j = 0; j < 8; ++j)
        vf[c][j] = (__bf16)vs[w][(lg * 8 + j) * 64 + c * 16 + lr];
  }
  f32x4_t o[4] = {};
#pragma unroll
  for (int c = 0; c < 4; ++c)
    o[c] = __builtin_amdgcn_mfma_f32_16x16x32_bf16(pf, vf[c], o[c], 0, 0, 0);

  bf16* ob = out + (size_t)t * 1024;
#pragma unroll
  for (int c = 0; c < 4; ++c)
#pragma unroll
    for (int j = 0; j < 4; ++j)
      ob[(lg * 4 + j) * 64 + c * 16 + lr] = __float2bfloat16(o[c][j]);
}

// ---------------------------------------------------------------- launch
extern "C" void kernel_launch(void* const* d_in, const int* in_sizes, int n_in,
                              void* d_out, int out_size, void* d_ws, size_t ws_size,
                              hipStream_t stream) {
  const float* x    = (const float*)d_in[0];  // [16384,1024]
  const float* Wqkv = (const float*)d_in[1];  // [1024,3072]
  const float* bqkv = (const float*)d_in[2];  // [3072]
  const float* Wout = (const float*)d_in[3];  // [1024,1024]
  const float* bout = (const float*)d_in[4];  // [1024]
  float* y = (float*)d_out;                   // [16384,1024]

  const int T = 16384, HD = 1024, N1 = 3072;

  char* ws = (char*)d_ws;
  size_t off = 0;
  bf16* ao  = (bf16*)(ws + off); off += (size_t)T * HD * 2;   // attention output
  bf16* w1t = (bf16*)(ws + off); off += (size_t)N1 * HD * 2;
  bf16* w2t = (bf16*)(ws + off); off += (size_t)HD * HD * 2;
  bf16* qkv = (bf16*)(ws + off); off += (size_t)T * N1 * 2;
  if (ws_size < off) return;

  prep_t<<<3072 + 1024, 256, 0, stream>>>(Wqkv, Wout, w1t, w2t);
  gemm256f<12><<<256, 512, 0, stream>>>(x, w1t, bqkv, qkv);
  attn_tok<<<T / 4, 256, 0, stream>>>(qkv, ao);
  gemm256p<0, 4><<<256, 512, 0, stream>>>(ao, w2t, bout, y);
}

// Round 14
// 263.217 us; speedup vs baseline: 1.1859x; 1.1859x over previous
//
#include <hip/hip_runtime.h>
#include <hip/hip_bf16.h>

using bf16 = __hip_bfloat16;
typedef __bf16 bf16x8_t __attribute__((ext_vector_type(8)));
typedef float f32x4_t __attribute__((ext_vector_type(4)));

// ---------------------------------------------------------------- helpers
__device__ __forceinline__ void gl16(bf16* l, const bf16* g) {
  // async global->LDS, 16B per lane; LDS dest must be linear (base + lane*16)
  __builtin_amdgcn_global_load_lds(
      (const __attribute__((address_space(1))) unsigned int*)g,
      (__attribute__((address_space(3))) unsigned int*)l, 16, 0, 0);
}

#define BARRIER() do { asm volatile("" ::: "memory"); __builtin_amdgcn_s_barrier(); asm volatile("" ::: "memory"); } while (0)
#define WAITVM(N) asm volatile("s_waitcnt vmcnt(" #N ")" ::: "memory")

// ---------------------------------------------------------------- prep: transpose both W (f32 -> bf16, [R][C] -> [C][R])
__global__ __launch_bounds__(256) void prep_t(const float* __restrict__ Wqkv,
                                              const float* __restrict__ Wout,
                                              bf16* __restrict__ w1t,
                                              bf16* __restrict__ w2t) {
  __shared__ float t[32][33];
  const int bid = blockIdx.x;
  const float* in; bf16* out; int R, C, gx, gy;
  if (bid < 3072) {
    in = Wqkv; out = w1t; R = 1024; C = 3072;
    gx = bid % 96; gy = bid / 96;
  } else {
    int idx = bid - 3072; in = Wout; out = w2t; R = 1024; C = 1024;
    gx = idx & 31; gy = idx >> 5;
  }
  int bx = gx * 32, by = gy * 32;
  int tx = threadIdx.x & 31, ty = threadIdx.x >> 5;  // ty 0..7
#pragma unroll
  for (int r = 0; r < 32; r += 8)
    t[ty + r][tx] = in[(size_t)(by + ty + r) * C + bx + tx];
  __syncthreads();
#pragma unroll
  for (int r = 0; r < 32; r += 8)
    out[(size_t)(bx + ty + r) * R + by + tx] = __float2bfloat16(t[tx][ty + r]);
}

// ---------------------------------------------------------------- x -> bf16 convert (vectorized)
__global__ __launch_bounds__(256) void cvt_f32_bf16(const float* __restrict__ in,
                                                    bf16* __restrict__ out, int n4) {
  int i = blockIdx.x * 256 + threadIdx.x;
  if (i >= n4) return;
  float4 v = ((const float4*)in)[i];
  union { ushort4 u; bf16 b[4]; } o;
  o.b[0] = __float2bfloat16(v.x);
  o.b[1] = __float2bfloat16(v.y);
  o.b[2] = __float2bfloat16(v.z);
  o.b[3] = __float2bfloat16(v.w);
  ((ushort4*)out)[i] = o.u;
}

// ---------------------------------------------------------------- shared GEMM pieces (R12-verified)
__device__ __forceinline__ void readA(const bf16* lb, int half, int wr, int lr, int lg, int exr,
                                      bf16x8_t (&af)[4][2]) {
  const bf16* ab = lb + half * 8192;
#pragma unroll
  for (int mi = 0; mi < 4; ++mi) {
    int R = wr * 64 + mi * 16 + lr;
    af[mi][0] = *(const bf16x8_t*)(ab + R * 64 + ((lg * 8) ^ exr));
    af[mi][1] = *(const bf16x8_t*)(ab + R * 64 + ((32 + lg * 8) ^ exr));
  }
}
__device__ __forceinline__ void readB(const bf16* lb, int half, int wc, int lr, int lg, int exr,
                                      bf16x8_t (&bfr)[2][2]) {
  const bf16* bb = lb + (2 + half) * 8192;
#pragma unroll
  for (int ni = 0; ni < 2; ++ni) {
    int R = wc * 32 + ni * 16 + lr;
    bfr[ni][0] = *(const bf16x8_t*)(bb + R * 64 + ((lg * 8) ^ exr));
    bfr[ni][1] = *(const bf16x8_t*)(bb + R * 64 + ((32 + lg * 8) ^ exr));
  }
}

template <int MH, int NH>
__device__ __forceinline__ void mfma16(bf16x8_t (&af)[4][2], bf16x8_t (&bfr)[2][2],
                                       f32x4_t (&acc)[8][4]) {
  __builtin_amdgcn_s_setprio(1);
#pragma unroll
  for (int mi = 0; mi < 4; ++mi)
#pragma unroll
    for (int ni = 0; ni < 2; ++ni) {
      f32x4_t& a = acc[MH * 4 + mi][NH * 2 + ni];
      a = __builtin_amdgcn_mfma_f32_16x16x32_bf16(af[mi][0], bfr[ni][0], a, 0, 0, 0);
      a = __builtin_amdgcn_mfma_f32_16x16x32_bf16(af[mi][1], bfr[ni][1], a, 0, 0, 0);
    }
  __builtin_amdgcn_s_setprio(0);
}

// ---------------------------------------------------------------- 256x256 bf16 GEMM, R12 schedule + per-tile hoisted pointers
// C[M=16384, N=NWGX*256] = A @ Bt^T + bias. K=1024 (16 K-steps of BK=64), grid 256x512thr,
// persistent TT=NWGX/4 tiles/block. Per tile: bases pA=A+(m0+srow)*K+colg (A addr =
// pA + h*65536 + s*64) and pB=Bt+(n0+browc0)*K+colg (pB + h*32768 + s*64) computed ONCE.
// Inner steps 0..13 uniform (unroll-2 -> static parity); steps 14/15 peeled with next-tile
// bases pAn/pBn. Verified call-by-call identical to R12's flattened schedule: ph-slot
// targets, parities, WAITVM(4) steady / WAITVM(0) at last-tile s14, post-wait af1/b0 reads.
template <int OUT_BF16, int NWGX>
__global__ __launch_bounds__(512, 2) void gemm256p(const bf16* __restrict__ A,
                                                   const bf16* __restrict__ Bt,
                                                   const float* __restrict__ bias,
                                                   void* __restrict__ Cv) {
  constexpr int K = 1024;
  constexpr int N = NWGX * 256;
  constexpr int TT = NWGX / 4;
  constexpr int CPX = NWGX * 8;

  __shared__ __align__(16) bf16 lds[65536];
  const int tid = threadIdx.x;
  const int bx = blockIdx.x;

  const int wid = tid >> 6, lane = tid & 63;
  const int wr = wid >> 2, wc = wid & 3;
  const int lr = lane & 15, lg = lane >> 4;
  const int exr = (lr & 7) << 3;

  const int srow = tid >> 3;
  const int colg = ((((tid & 7) * 16) ^ ((srow & 7) << 4)) >> 1);
  const int browc0 = (srow >> 5) * 64 + (srow & 31);

  auto tileMN = [&](int tt, int& m0, int& n0) {
    int orig = bx + (tt << 8);
    int swz = (orig & 7) * CPX + (orig >> 3);
    m0 = (swz / NWGX) * 256;
    n0 = (swz % NWGX) * 256;
  };

  bf16* const ldsSt = lds + tid * 8;
  auto stA = [&](const bf16* pA, int s, int h, int par) {
    const bf16* g0 = pA + h * 65536 + s * 64;
    bf16* l = ldsSt + par * 32768 + h * 8192;
    gl16(l, g0); gl16(l + 4096, g0 + (size_t)128 * K);
  };
  auto stB = [&](const bf16* pB, int s, int h, int par) {
    const bf16* g0 = pB + h * 32768 + s * 64;
    bf16* l = ldsSt + par * 32768 + (2 + h) * 8192;
    gl16(l, g0); gl16(l + 4096, g0 + (size_t)128 * K);
  };

  f32x4_t acc[8][4] = {};
  bf16x8_t af1[4][2], af2[4][2], b0[2][2], b1[2][2];

  int m0, n0;
  tileMN(0, m0, n0);
  const bf16* pA = A + (size_t)(m0 + srow) * K + colg;
  const bf16* pB = Bt + (size_t)(n0 + browc0) * K + colg;

  // prologue: step 0 fully staged + {Ah0,Bh0}(1) in flight (order = R12)
  stA(pA, 0, 0, 0); stB(pB, 0, 0, 0); stA(pA, 0, 1, 0); stB(pB, 0, 1, 0);
  stA(pA, 1, 0, 1); stB(pB, 1, 0, 1);
  WAITVM(4);
  BARRIER();
  readA(lds, 0, wr, lr, lg, exr, af1);
  readB(lds, 0, wc, lr, lg, exr, b0);

  for (int tt = 0; tt < TT; ++tt) {
    const bool last = (tt == TT - 1);
    int m0x, n0x;
    tileMN(last ? tt : tt + 1, m0x, n0x);
    const bf16* pAn = A + (size_t)(m0x + srow) * K + colg;
    const bf16* pBn = Bt + (size_t)(n0x + browc0) * K + colg;

#pragma unroll 2
    for (int s = 0; s < 14; ++s) {
      const int par = s & 1, parn = par ^ 1;
      const bf16* cb = lds + par * 32768;
      const bf16* nb = lds + parn * 32768;

      stA(pA, s + 1, 1, parn);
      BARRIER();
      readB(cb, 1, wc, lr, lg, exr, b1);
      mfma16<0, 0>(af1, b0, acc);

      stB(pB, s + 1, 1, parn);
      BARRIER();
      readA(cb, 1, wr, lr, lg, exr, af2);
      mfma16<0, 1>(af1, b1, acc);

      stA(pA, s + 2, 0, par);
      BARRIER();
      mfma16<1, 0>(af2, b0, acc);

      stB(pB, s + 2, 0, par);
      WAITVM(4);
      BARRIER();
      readA(nb, 0, wr, lr, lg, exr, af1);
      readB(nb, 0, wc, lr, lg, exr, b0);
      mfma16<1, 1>(af2, b1, acc);
    }
    {  // s = 14 (par 0): ph3/ph4 stage NEXT tile step 0 (parity 0)
      const bf16* cb = lds;
      const bf16* nb = lds + 32768;
      stA(pA, 15, 1, 1);
      BARRIER();
      readB(cb, 1, wc, lr, lg, exr, b1);
      mfma16<0, 0>(af1, b0, acc);

      stB(pB, 15, 1, 1);
      BARRIER();
      readA(cb, 1, wr, lr, lg, exr, af2);
      mfma16<0, 1>(af1, b1, acc);

      if (!last) stA(pAn, 0, 0, 0);
      BARRIER();
      mfma16<1, 0>(af2, b0, acc);

      if (!last) { stB(pBn, 0, 0, 0); WAITVM(4); } else { WAITVM(0); }
      BARRIER();
      readA(nb, 0, wr, lr, lg, exr, af1);
      readB(nb, 0, wc, lr, lg, exr, b0);
      mfma16<1, 1>(af2, b1, acc);
    }
    {  // s = 15 (par 1): ph1/ph2 stage next(0,h1); ph3/ph4 stage next(1,h0)
      const bf16* cb = lds + 32768;
      const bf16* nb = lds;
      if (!last) stA(pAn, 0, 1, 0);
      BARRIER();
      readB(cb, 1, wc, lr, lg, exr, b1);
      mfma16<0, 0>(af1, b0, acc);

      if (!last) stB(pBn, 0, 1, 0);
      BARRIER();
      readA(cb, 1, wr, lr, lg, exr, af2);
      mfma16<0, 1>(af1, b1, acc);

      if (!last) stA(pAn, 1, 0, 1);
      BARRIER();
      mfma16<1, 0>(af2, b0, acc);

      if (!last) { stB(pBn, 1, 0, 1); WAITVM(4); }
      BARRIER();
      if (!last) {
        readA(nb, 0, wr, lr, lg, exr, af1);
        readB(nb, 0, wc, lr, lg, exr, b0);
      }
      mfma16<1, 1>(af2, b1, acc);
    }

    // dump finished tile tt at (m0, n0); n innermost -> line-complete stores
    BARRIER();
    {
      float bv[4];
#pragma unroll
      for (int n = 0; n < 4; ++n) bv[n] = bias[n0 + wc * 64 + n * 16 + lr];
#pragma unroll
      for (int m = 0; m < 8; ++m) {
        int row = m0 + wr * 128 + m * 16 + lg * 4;
#pragma unroll
        for (int j = 0; j < 4; ++j) {
#pragma unroll
          for (int n = 0; n < 4; ++n) {
            int col = n0 + wc * 64 + n * 16 + lr;
            float v = acc[m][n][j] + bv[n];
            if (OUT_BF16)
              ((bf16*)Cv)[(size_t)(row + j) * N + col] = __float2bfloat16(v);
            else
              ((float*)Cv)[(size_t)(row + j) * N + col] = v;
            acc[m][n][j] = 0.f;
          }
        }
      }
    }
    pA = pAn; pB = pBn; m0 = m0x; n0 = n0x;
  }
}

// ---------------------------------------------------------------- per-token head-mixing attention (MFMA)
// qkv[t][0:1024]=q, [1024:2048]=k, [2048:3072]=v ; head layout idx = h*64+d
// logits[qh][kh] = 0.125 * dot(q[qh], k[kh]); softmax over kh; out[qh][d] = sum_kh p*v[kh][d]
#define PSTR 48
__global__ __launch_bounds__(256) void attn_tok(const bf16* __restrict__ qkv,
                                                bf16* __restrict__ out) {
  __shared__ __align__(16) bf16 vs[4][1024];
  __shared__ __align__(16) bf16 ps[4][16 * PSTR];
  const int w = threadIdx.x >> 6, l = threadIdx.x & 63;
  const int t = blockIdx.x * 4 + w;
  const int lr = l & 15, lg = l >> 4;
  const bf16* base = qkv + (size_t)t * 3072;

  bf16x8_t v0 = *(const bf16x8_t*)(base + 2048 + l * 16);
  bf16x8_t v1 = *(const bf16x8_t*)(base + 2048 + l * 16 + 8);
  *(bf16x8_t*)(&vs[w][l * 16]) = v0;
  *(bf16x8_t*)(&vs[w][l * 16 + 8]) = v1;

  *(unsigned long long*)(&ps[w][(l >> 2) * PSTR + 16 + (l & 3) * 4]) = 0ULL;

  const bf16* qp = base + lr * 64 + lg * 8;
  const bf16* kp = base + 1024 + lr * 64 + lg * 8;
  bf16x8_t qa0 = *(const bf16x8_t*)qp;
  bf16x8_t ka0 = *(const bf16x8_t*)kp;
  bf16x8_t qa1 = *(const bf16x8_t*)(qp + 32);
  bf16x8_t ka1 = *(const bf16x8_t*)(kp + 32);
  f32x4_t s = {};
  s = __builtin_amdgcn_mfma_f32_16x16x32_bf16(qa0, ka0, s, 0, 0, 0);
  s = __builtin_amdgcn_mfma_f32_16x16x32_bf16(qa1, ka1, s, 0, 0, 0);

#pragma unroll
  for (int j = 0; j < 4; ++j) {
    float x = s[j] * 0.125f;
    float mx = x;
#pragma unroll
    for (int off = 8; off; off >>= 1) mx = fmaxf(mx, __shfl_xor(mx, off, 16));
    float e = __expf(x - mx);
    float sum = e;
#pragma unroll
    for (int off = 8; off; off >>= 1) sum += __shfl_xor(sum, off, 16);
    ps[w][(lg * 4 + j) * PSTR + lr] = __float2bfloat16(e / sum);
  }

  bf16x8_t pf = *(const bf16x8_t*)(&ps[w][lr * PSTR + lg * 8]);
  bf16x8_t vf[4] = {};
  if (l < 32) {
#pragma unroll
    for (int c = 0; c < 4; ++c)
#pragma unroll
      for (int j = 0; j < 8; ++j)
        vf[c][j] = (__bf16)vs[w][(lg * 8 + j) * 64 + c * 16 + lr];
  }
  f32x4_t o[4] = {};
#pragma unroll
  for (int c = 0; c < 4; ++c)
    o[c] = __builtin_amdgcn_mfma_f32_16x16x32_bf16(pf, vf[c], o[c], 0, 0, 0);

  bf16* ob = out + (size_t)t * 1024;
#pragma unroll
  for (int c = 0; c < 4; ++c)
#pragma unroll
    for (int j = 0; j < 4; ++j)
      ob[(lg * 4 + j) * 64 + c * 16 + lr] = __float2bfloat16(o[c][j]);
}

// ---------------------------------------------------------------- launch
extern "C" void kernel_launch(void* const* d_in, const int* in_sizes, int n_in,
                              void* d_out, int out_size, void* d_ws, size_t ws_size,
                              hipStream_t stream) {
  const float* x    = (const float*)d_in[0];  // [16384,1024]
  const float* Wqkv = (const float*)d_in[1];  // [1024,3072]
  const float* bqkv = (const float*)d_in[2];  // [3072]
  const float* Wout = (const float*)d_in[3];  // [1024,1024]
  const float* bout = (const float*)d_in[4];  // [1024]
  float* y = (float*)d_out;                   // [16384,1024]

  const int T = 16384, HD = 1024, N1 = 3072;

  char* ws = (char*)d_ws;
  size_t off = 0;
  bf16* xb  = (bf16*)(ws + off); off += (size_t)T * HD * 2;   // x bf16 (reused as attn out)
  bf16* w1t = (bf16*)(ws + off); off += (size_t)N1 * HD * 2;
  bf16* w2t = (bf16*)(ws + off); off += (size_t)HD * HD * 2;
  bf16* qkv = (bf16*)(ws + off); off += (size_t)T * N1 * 2;
  if (ws_size < off) return;
  bf16* ao = xb;  // xb dead after GEMM1; reuse as attention output

  cvt_f32_bf16<<<T * HD / 4 / 256, 256, 0, stream>>>(x, xb, T * HD / 4);
  prep_t<<<3072 + 1024, 256, 0, stream>>>(Wqkv, Wout, w1t, w2t);
  gemm256p<1, 12><<<256, 512, 0, stream>>>(xb, w1t, bqkv, qkv);
  attn_tok<<<T / 4, 256, 0, stream>>>(qkv, ao);
  gemm256p<0, 4><<<256, 512, 0, stream>>>(ao, w2t, bout, y);
}

// Round 15
// 201.809 us; speedup vs baseline: 1.5468x; 1.3043x over previous
//
#include <hip/hip_runtime.h>
#include <hip/hip_bf16.h>

using bf16 = __hip_bfloat16;
typedef __bf16 bf16x8_t __attribute__((ext_vector_type(8)));
typedef float f32x4_t __attribute__((ext_vector_type(4)));

// ---------------------------------------------------------------- helpers
__device__ __forceinline__ void gl16(bf16* l, const bf16* g) {
  // async global->LDS, 16B per lane; LDS dest must be linear (base + lane*16)
  __builtin_amdgcn_global_load_lds(
      (const __attribute__((address_space(1))) unsigned int*)g,
      (__attribute__((address_space(3))) unsigned int*)l, 16, 0, 0);
}

#define BARRIER() do { asm volatile("" ::: "memory"); __builtin_amdgcn_s_barrier(); asm volatile("" ::: "memory"); } while (0)
#define WAITVM(N) asm volatile("s_waitcnt vmcnt(" #N ")" ::: "memory")

// ---------------------------------------------------------------- fused prep: cvt x + transpose both W
__global__ __launch_bounds__(256) void prep_fused(const float* __restrict__ x,
                                                  const float* __restrict__ Wqkv,
                                                  const float* __restrict__ Wout,
                                                  bf16* __restrict__ xb,
                                                  bf16* __restrict__ w1t,
                                                  bf16* __restrict__ w2t) {
  __shared__ float t[32][33];
  const int bid = blockIdx.x;
  if (bid < 16384) {  // cvt: 4 f32 per thread
    int i = bid * 256 + threadIdx.x;
    float4 v = ((const float4*)x)[i];
    union { ushort4 u; bf16 b[4]; } o;
    o.b[0] = __float2bfloat16(v.x);
    o.b[1] = __float2bfloat16(v.y);
    o.b[2] = __float2bfloat16(v.z);
    o.b[3] = __float2bfloat16(v.w);
    ((ushort4*)xb)[i] = o.u;
    return;
  }
  const float* in; bf16* out; int R, C, gx, gy;
  if (bid < 16384 + 3072) {
    int idx = bid - 16384; in = Wqkv; out = w1t; R = 1024; C = 3072;
    gx = idx % 96; gy = idx / 96;
  } else {
    int idx = bid - 16384 - 3072; in = Wout; out = w2t; R = 1024; C = 1024;
    gx = idx & 31; gy = idx >> 5;
  }
  int bx = gx * 32, by = gy * 32;
  int tx = threadIdx.x & 31, ty = threadIdx.x >> 5;  // ty 0..7
#pragma unroll
  for (int r = 0; r < 32; r += 8)
    t[ty + r][tx] = in[(size_t)(by + ty + r) * C + bx + tx];
  __syncthreads();
#pragma unroll
  for (int r = 0; r < 32; r += 8)
    out[(size_t)(bx + ty + r) * R + by + tx] = __float2bfloat16(t[tx][ty + r]);
}

// ---------------------------------------------------------------- 256x256 bf16 GEMM, R5 schedule (no sched_barrier pinning)
// C[M=16384, N=NWGX*256] = A @ Bt^T + bias. K=1024 (16 K-steps of BK=64), grid 256x512thr.
// LDS: 2 bufs x {Ah0,Ah1,Bh0,Bh1} halves of [128 rows][64 cols] bf16.
// 4 phases/K-step, 1 barrier each; fragment sets (af1,af2,b0,b1) read one phase AHEAD of
// use — reads and current-phase MFMAs are independent, and the compiler is free to
// interleave them so the LDS pipe overlaps the MFMA pipe.
// ph4 stages B(g+2,h0) then WAITVM(4) -> step g+1 fully resident.
// Swizzle: 8-elem chunk ^= row&7 on read; inverse pre-applied on staging global source.

__device__ __forceinline__ void readA(const bf16* lb, int half, int wr, int lr, int lg, int exr,
                                      bf16x8_t (&af)[4][2]) {
  const bf16* ab = lb + half * 8192;
#pragma unroll
  for (int mi = 0; mi < 4; ++mi) {
    int R = wr * 64 + mi * 16 + lr;
    af[mi][0] = *(const bf16x8_t*)(ab + R * 64 + ((lg * 8) ^ exr));
    af[mi][1] = *(const bf16x8_t*)(ab + R * 64 + ((32 + lg * 8) ^ exr));
  }
}
__device__ __forceinline__ void readB(const bf16* lb, int half, int wc, int lr, int lg, int exr,
                                      bf16x8_t (&bfr)[2][2]) {
  const bf16* bb = lb + (2 + half) * 8192;
#pragma unroll
  for (int ni = 0; ni < 2; ++ni) {
    int R = wc * 32 + ni * 16 + lr;
    bfr[ni][0] = *(const bf16x8_t*)(bb + R * 64 + ((lg * 8) ^ exr));
    bfr[ni][1] = *(const bf16x8_t*)(bb + R * 64 + ((32 + lg * 8) ^ exr));
  }
}

template <int MH, int NH>
__device__ __forceinline__ void mfma16(bf16x8_t (&af)[4][2], bf16x8_t (&bfr)[2][2],
                                       f32x4_t (&acc)[8][4]) {
  __builtin_amdgcn_s_setprio(1);
#pragma unroll
  for (int mi = 0; mi < 4; ++mi)
#pragma unroll
    for (int ni = 0; ni < 2; ++ni) {
      f32x4_t& a = acc[MH * 4 + mi][NH * 2 + ni];
      a = __builtin_amdgcn_mfma_f32_16x16x32_bf16(af[mi][0], bfr[ni][0], a, 0, 0, 0);
      a = __builtin_amdgcn_mfma_f32_16x16x32_bf16(af[mi][1], bfr[ni][1], a, 0, 0, 0);
    }
  __builtin_amdgcn_s_setprio(0);
}

template <int OUT_BF16, int NWGX>
__global__ __launch_bounds__(512, 2) void gemm256p(const bf16* __restrict__ A,
                                                   const bf16* __restrict__ Bt,
                                                   const float* __restrict__ bias,
                                                   void* __restrict__ Cv) {
  constexpr int K = 1024;
  constexpr int N = NWGX * 256;
  constexpr int TT = NWGX / 4;     // output tiles per block (grid fixed at 256)
  constexpr int G = TT * 16;       // flattened K-steps
  constexpr int CPX = NWGX * 8;    // tiles per XCD chunk

  __shared__ __align__(16) bf16 lds[65536];  // 128 KiB
  const int tid = threadIdx.x;
  const int bx = blockIdx.x;

  const int wid = tid >> 6, lane = tid & 63;
  const int wr = wid >> 2, wc = wid & 3;
  const int lr = lane & 15, lg = lane >> 4;
  const int exr = (lr & 7) << 3;

  const int srow = tid >> 3;
  const int colg = ((((tid & 7) * 16) ^ ((srow & 7) << 4)) >> 1);
  const int browc0 = (srow >> 5) * 64 + (srow & 31);

  auto tileMN = [&](int tt, int& m0, int& n0) {
    int orig = bx + (tt << 8);
    int swz = (orig & 7) * CPX + (orig >> 3);
    m0 = (swz / NWGX) * 256;
    n0 = (swz % NWGX) * 256;
  };

  auto stageA = [&](int g, int h) {
    if (g >= G) return;
    int m0, n0; tileMN(g >> 4, m0, n0);
    const bf16* g0 = A + (size_t)(m0 + h * 64 + srow) * K + (g & 15) * 64 + colg;
    bf16* l = lds + (g & 1) * 32768 + h * 8192 + tid * 8;
    gl16(l, g0); gl16(l + 4096, g0 + (size_t)128 * K);
  };
  auto stageB = [&](int g, int h) {
    if (g >= G) return;
    int m0, n0; tileMN(g >> 4, m0, n0);
    const bf16* g0 = Bt + (size_t)(n0 + browc0 + h * 32) * K + (g & 15) * 64 + colg;
    bf16* l = lds + (g & 1) * 32768 + (2 + h) * 8192 + tid * 8;
    gl16(l, g0); gl16(l + 4096, g0 + (size_t)128 * K);
  };

  f32x4_t acc[8][4] = {};
  bf16x8_t af1[4][2], af2[4][2], b0[2][2], b1[2][2];

  // prologue: K-step 0 fully staged + {Ah0,Bh0}(1) in flight
  stageA(0, 0); stageB(0, 0); stageA(0, 1); stageB(0, 1);
  stageA(1, 0); stageB(1, 0);
  WAITVM(4);
  BARRIER();
  readA(lds, 0, wr, lr, lg, exr, af1);   // Ah0(0)
  readB(lds, 0, wc, lr, lg, exr, b0);    // Bh0(0)

  for (int g = 0; g < G; ++g) {
    const bf16* cb = lds + (g & 1) * 32768;
    const bf16* nb = lds + ((g & 1) ^ 1) * 32768;

    // phase 1: Q(0,0) = af1 x b0 ; prefetch b1 (Bh1 cur)  [reads free to mix with MFMA]
    stageA(g + 1, 1);
    BARRIER();
    readB(cb, 1, wc, lr, lg, exr, b1);
    mfma16<0, 0>(af1, b0, acc);

    // phase 2: Q(0,1) = af1 x b1 ; prefetch af2 (Ah1 cur)
    stageB(g + 1, 1);
    BARRIER();
    readA(cb, 1, wr, lr, lg, exr, af2);
    mfma16<0, 1>(af1, b1, acc);

    // phase 3: Q(1,0) = af2 x b0
    stageA(g + 2, 0);
    BARRIER();
    mfma16<1, 0>(af2, b0, acc);

    // phase 4: Q(1,1) = af2 x b1 ; prefetch af1,b0 from NEXT buffer
    stageB(g + 2, 0);
    if (g < G - 2) { WAITVM(4); } else { WAITVM(0); }
    BARRIER();
    if (g < G - 1) {
      readA(nb, 0, wr, lr, lg, exr, af1);
      readB(nb, 0, wc, lr, lg, exr, b0);
    }
    mfma16<1, 1>(af2, b1, acc);

    if ((g & 15) == 15) {
      BARRIER();  // keep dump stores out of the last phase's read window
      // dump finished tile; n innermost so each 64B C-line completes back-to-back
      int m0, n0; tileMN(g >> 4, m0, n0);
      float bv[4];
#pragma unroll
      for (int n = 0; n < 4; ++n) bv[n] = bias[n0 + wc * 64 + n * 16 + lr];
#pragma unroll
      for (int m = 0; m < 8; ++m) {
        int row = m0 + wr * 128 + m * 16 + lg * 4;
#pragma unroll
        for (int j = 0; j < 4; ++j) {
#pragma unroll
          for (int n = 0; n < 4; ++n) {
            int col = n0 + wc * 64 + n * 16 + lr;
            float v = acc[m][n][j] + bv[n];
            if (OUT_BF16)
              ((bf16*)Cv)[(size_t)(row + j) * N + col] = __float2bfloat16(v);
            else
              ((float*)Cv)[(size_t)(row + j) * N + col] = v;
            acc[m][n][j] = 0.f;
          }
        }
      }
    }
  }
}

// ---------------------------------------------------------------- per-token head-mixing attention (MFMA)
// qkv[t][0:1024]=q, [1024:2048]=k, [2048:3072]=v ; head layout idx = h*64+d
// logits[qh][kh] = 0.125 * dot(q[qh], k[kh]); softmax over kh; out[qh][d] = sum_kh p*v[kh][d]
#define PSTR 48
__global__ __launch_bounds__(256) void attn_tok(const bf16* __restrict__ qkv,
                                                bf16* __restrict__ out) {
  __shared__ __align__(16) bf16 vs[4][1024];
  __shared__ __align__(16) bf16 ps[4][16 * PSTR];
  const int w = threadIdx.x >> 6, l = threadIdx.x & 63;
  const int t = blockIdx.x * 4 + w;
  const int lr = l & 15, lg = l >> 4;
  const bf16* base = qkv + (size_t)t * 3072;

  bf16x8_t v0 = *(const bf16x8_t*)(base + 2048 + l * 16);
  bf16x8_t v1 = *(const bf16x8_t*)(base + 2048 + l * 16 + 8);
  *(bf16x8_t*)(&vs[w][l * 16]) = v0;
  *(bf16x8_t*)(&vs[w][l * 16 + 8]) = v1;

  *(unsigned long long*)(&ps[w][(l >> 2) * PSTR + 16 + (l & 3) * 4]) = 0ULL;

  const bf16* qp = base + lr * 64 + lg * 8;
  const bf16* kp = base + 1024 + lr * 64 + lg * 8;
  bf16x8_t qa0 = *(const bf16x8_t*)qp;
  bf16x8_t ka0 = *(const bf16x8_t*)kp;
  bf16x8_t qa1 = *(const bf16x8_t*)(qp + 32);
  bf16x8_t ka1 = *(const bf16x8_t*)(kp + 32);
  f32x4_t s = {};
  s = __builtin_amdgcn_mfma_f32_16x16x32_bf16(qa0, ka0, s, 0, 0, 0);
  s = __builtin_amdgcn_mfma_f32_16x16x32_bf16(qa1, ka1, s, 0, 0, 0);

#pragma unroll
  for (int j = 0; j < 4; ++j) {
    float x = s[j] * 0.125f;
    float mx = x;
#pragma unroll
    for (int off = 8; off; off >>= 1) mx = fmaxf(mx, __shfl_xor(mx, off, 16));
    float e = __expf(x - mx);
    float sum = e;
#pragma unroll
    for (int off = 8; off; off >>= 1) sum += __shfl_xor(sum, off, 16);
    ps[w][(lg * 4 + j) * PSTR + lr] = __float2bfloat16(e / sum);
  }

  bf16x8_t pf = *(const bf16x8_t*)(&ps[w][lr * PSTR + lg * 8]);
  bf16x8_t vf[4] = {};
  if (l < 32) {
#pragma unroll
    for (int c = 0; c < 4; ++c)
#pragma unroll
      for (int j = 0; j < 8; ++j)
        vf[c][j] = (__bf16)vs[w][(lg * 8 + j) * 64 + c * 16 + lr];
  }
  f32x4_t o[4] = {};
#pragma unroll
  for (int c = 0; c < 4; ++c)
    o[c] = __builtin_amdgcn_mfma_f32_16x16x32_bf16(pf, vf[c], o[c], 0, 0, 0);

  bf16* ob = out + (size_t)t * 1024;
#pragma unroll
  for (int c = 0; c < 4; ++c)
#pragma unroll
    for (int j = 0; j < 4; ++j)
      ob[(lg * 4 + j) * 64 + c * 16 + lr] = __float2bfloat16(o[c][j]);
}

// ---------------------------------------------------------------- launch
extern "C" void kernel_launch(void* const* d_in, const int* in_sizes, int n_in,
                              void* d_out, int out_size, void* d_ws, size_t ws_size,
                              hipStream_t stream) {
  const float* x    = (const float*)d_in[0];  // [16384,1024]
  const float* Wqkv = (const float*)d_in[1];  // [1024,3072]
  const float* bqkv = (const float*)d_in[2];  // [3072]
  const float* Wout = (const float*)d_in[3];  // [1024,1024]
  const float* bout = (const float*)d_in[4];  // [1024]
  float* y = (float*)d_out;                   // [16384,1024]

  const int T = 16384, HD = 1024, N1 = 3072;

  char* ws = (char*)d_ws;
  size_t off = 0;
  bf16* xb  = (bf16*)(ws + off); off += (size_t)T * HD * 2;
  bf16* w1t = (bf16*)(ws + off); off += (size_t)N1 * HD * 2;
  bf16* w2t = (bf16*)(ws + off); off += (size_t)HD * HD * 2;
  bf16* qkv = (bf16*)(ws + off); off += (size_t)T * N1 * 2;
  if (ws_size < off) return;
  bf16* ao = xb;  // xb dead after GEMM1; reuse as attention output

  prep_fused<<<16384 + 3072 + 1024, 256, 0, stream>>>(x, Wqkv, Wout, xb, w1t, w2t);
  gemm256p<1, 12><<<256, 512, 0, stream>>>(xb, w1t, bqkv, qkv);
  attn_tok<<<T / 4, 256, 0, stream>>>(qkv, ao);
  gemm256p<0, 4><<<256, 512, 0, stream>>>(ao, w2t, bout, y);
}